// Round 1
// baseline (7893.095 us; speedup 1.0000x reference)
//
#include <hip/hip_runtime.h>
#include <hip/hip_fp16.h>
#include <stdint.h>

#define T_SEQ 1024
#define NB    64
#define VOCAB 34
#define NSPK  128
#define DTXT  512
#define HID   256
#define NMEL  80
#define GROWS 1024   // 4*HID gate rows
#define DROWS 768    // decoder rows actually used: i,g,o

typedef _Float16 f16;
typedef _Float16 f16x2 __attribute__((ext_vector_type(2)));

__device__ __forceinline__ float fdot2f(uint32_t a, uint32_t b, float c) {
  return __builtin_amdgcn_fdot2(__builtin_bit_cast(f16x2, a),
                                __builtin_bit_cast(f16x2, b), c, false);
}
__device__ __forceinline__ float sigm(float x) { return 1.0f / (1.0f + __expf(-x)); }

// ---------------- prep kernels ----------------

// TP[dir][v][row] = emb_text[v] . Wih[dir][row][0:512]
__global__ void k_tp(const float* __restrict__ Wf, const float* __restrict__ Wb,
                     const float* __restrict__ emb_text, float* __restrict__ TP) {
  int blk = blockIdx.x; int dir = blk / VOCAB; int v = blk - dir * VOCAB;
  const float* W = dir ? Wb : Wf;
  const float* e = emb_text + (size_t)v * DTXT;
  for (int r = threadIdx.x; r < GROWS; r += 256) {
    const float* wr = W + (size_t)r * 576;
    float a0 = 0, a1 = 0, a2 = 0, a3 = 0;
    for (int d = 0; d < DTXT; d += 4) {
      a0 += e[d] * wr[d];     a1 += e[d+1] * wr[d+1];
      a2 += e[d+2] * wr[d+2]; a3 += e[d+3] * wr[d+3];
    }
    TP[(size_t)(dir * VOCAB + v) * GROWS + r] = (a0 + a1) + (a2 + a3);
  }
}

// SP[dir][s][row] = emb_spk[s] . Wih[dir][row][512:576] + bih[row] + bhh[row]
__global__ void k_sp(const float* __restrict__ Wf, const float* __restrict__ Wb,
                     const float* __restrict__ bihf, const float* __restrict__ bhhf,
                     const float* __restrict__ bihb, const float* __restrict__ bhhb,
                     const float* __restrict__ emb_spk, float* __restrict__ SP) {
  int blk = blockIdx.x; int dir = blk >> 7; int s = blk & 127;
  const float* W  = dir ? Wb : Wf;
  const float* bi = dir ? bihb : bihf;
  const float* bh = dir ? bhhb : bhhf;
  const float* e  = emb_spk + (size_t)s * 64;
  for (int r = threadIdx.x; r < GROWS; r += 256) {
    const float* wr = W + (size_t)r * 576 + 512;
    float acc = bi[r] + bh[r];
    for (int d = 0; d < 64; ++d) acc += e[d] * wr[d];
    SP[(size_t)(dir * NSPK + s) * GROWS + r] = acc;
  }
}

// Whh (both dirs) -> f16, same layout [2][1024][256]
__global__ void k_whh(const float* __restrict__ Whhf, const float* __restrict__ Whhb,
                      f16* __restrict__ WhhH) {
  int idx = blockIdx.x * 256 + threadIdx.x;
  if (idx < 2 * GROWS * HID) {
    int dir = idx >> 18; int rem = idx & (GROWS * HID - 1);
    WhhH[idx] = (f16)(dir ? Whhb[rem] : Whhf[rem]);
  }
}

// decoder weights, row-reordered to [i(256), g(256), o(256)] (f gate unused)
__global__ void k_decw(const float* __restrict__ Wih_d, const float* __restrict__ bih_d,
                       const float* __restrict__ bhh_d,
                       f16* __restrict__ WmH, f16* __restrict__ WdH, float* __restrict__ dbias) {
  int r = blockIdx.x;                 // 0..767
  int src = (r < 256) ? r : (r + 256);
  const float* w = Wih_d + (size_t)src * 592;
  for (int k = threadIdx.x; k < 592; k += 256) {
    float v = w[k];
    if (k < 80) WmH[(size_t)r * 80 + k] = (f16)v;
    else        WdH[(size_t)r * 512 + (k - 80)] = (f16)v;
  }
  if (threadIdx.x == 0) dbias[r] = bih_d[src] + bhh_d[src];
}

__global__ void k_misc(const float* __restrict__ Wfc, f16* __restrict__ WfcH,
                       unsigned int* __restrict__ flags) {
  int idx = blockIdx.x * 256 + threadIdx.x;
  if (idx < NMEL * HID) WfcH[idx] = (f16)Wfc[idx];
  if (idx < 256) flags[idx] = 0u;
}

// ---------------- encoder: persistent bi-LSTM ----------------
// 256 WGs: w = half*128 + dir*64 + b.  Each WG owns 128 hidden units (half),
// thread t owns gate row (t>>7)*256 + half*128 + (t&127); Whh row lives in VGPRs (f16).
// Halves (w, w+128) exchange h each step via agent-scope atomics + flags.
__launch_bounds__(512, 2)
__global__ void k_enc(const int* __restrict__ text_seq, const int* __restrict__ speaker_id,
                      const float* __restrict__ TP, const float* __restrict__ SP,
                      const uint32_t* __restrict__ WhhH_dw,
                      uint32_t* __restrict__ Hdw,            // Hhist [2][1024][64][128 dw] f16
                      unsigned int* __restrict__ flags) {
  __shared__ __align__(16) uint32_t h_lds[128];   // 256 f16
  __shared__ float g_lds[512];
  int w = blockIdx.x;
  int half = w >> 7;
  int dirb = w & 127; int dir = dirb >> 6; int b = dirb & 63;
  int tid = threadIdx.x;
  int gate = tid >> 7, ul = tid & 127;
  int unit = half * 128 + ul;
  int row = gate * 256 + unit;

  uint4 wv[32];
  {
    const uint4* wp4 = (const uint4*)(WhhH_dw + (size_t)(dir * GROWS + row) * 128);
    #pragma unroll
    for (int i = 0; i < 32; ++i) wv[i] = wp4[i];
  }
  float sp_val = SP[(size_t)(dir * NSPK + speaker_id[b]) * GROWS + row];
  const float* TPd = TP + (size_t)dir * VOCAB * GROWS;

  if (tid < 128) h_lds[tid] = 0u;
  float c_state = 0.0f;
  const unsigned int myF = (unsigned)(dirb * 2 + half);
  const unsigned int paF = (unsigned)(dirb * 2 + (half ^ 1));
  __syncthreads();

  for (int n = 0; n < T_SEQ; ++n) {
    int t_seq = dir ? (T_SEQ - 1 - n) : n;
    int v = text_seq[b * T_SEQ + t_seq];
    float x = TPd[(size_t)v * GROWS + row] + sp_val;

    float a0 = 0, a1 = 0, a2 = 0, a3 = 0;
    const uint4* h4 = (const uint4*)h_lds;
    #pragma unroll
    for (int c = 0; c < 32; ++c) {
      uint4 hv = h4[c];
      a0 = fdot2f(wv[c].x, hv.x, a0);
      a1 = fdot2f(wv[c].y, hv.y, a1);
      a2 = fdot2f(wv[c].z, hv.z, a2);
      a3 = fdot2f(wv[c].w, hv.w, a3);
    }
    g_lds[tid] = ((a0 + a1) + (a2 + a3)) + x;
    __syncthreads();                               // B1

    if (tid < 128) {
      float gi = g_lds[ul], gf = g_lds[128 + ul], gg = g_lds[256 + ul], go = g_lds[384 + ul];
      c_state = sigm(gf) * c_state + sigm(gi) * tanhf(gg);
      float h = sigm(go) * tanhf(c_state);
      ((f16*)h_lds)[unit] = (f16)h;                // own half into LDS
    }
    __syncthreads();                               // B2

    size_t hbase = ((size_t)(dir * T_SEQ + t_seq) * NB + b) * 128;
    if (tid < 64) {
      uint32_t d = h_lds[half * 64 + tid];
      __hip_atomic_store(Hdw + hbase + half * 64 + tid, d,
                         __ATOMIC_RELAXED, __HIP_MEMORY_SCOPE_AGENT);
    }
    __syncthreads();                               // B3 (drain stores before flag)
    if (tid == 0)
      __hip_atomic_store(&flags[myF], (unsigned)(n + 1),
                         __ATOMIC_RELEASE, __HIP_MEMORY_SCOPE_AGENT);
    if (tid < 64) {
      while (__hip_atomic_load(&flags[paF], __ATOMIC_RELAXED, __HIP_MEMORY_SCOPE_AGENT)
             < (unsigned)(n + 1)) { __builtin_amdgcn_s_sleep(2); }
      (void)__hip_atomic_load(&flags[paF], __ATOMIC_ACQUIRE, __HIP_MEMORY_SCOPE_AGENT);
      int ph = half ^ 1;
      uint32_t d = __hip_atomic_load(Hdw + hbase + ph * 64 + tid,
                                     __ATOMIC_RELAXED, __HIP_MEMORY_SCOPE_AGENT);
      h_lds[ph * 64 + tid] = d;
    }
    __syncthreads();                               // B4
  }
}

// ---------------- E projection: E[t][b][n] = cat(hf[t][b],hb[t][b]) . Wd[n] + dbias[n]
__launch_bounds__(256, 4)
__global__ void k_eproj(const uint32_t* __restrict__ Hdw, const uint32_t* __restrict__ WdH_dw,
                        const float* __restrict__ dbias, f16* __restrict__ E) {
  __shared__ __align__(16) uint32_t Asm[64][68];
  __shared__ __align__(16) uint32_t Wsm[64][68];
  int nt = blockIdx.x % 12;
  int t  = blockIdx.x / 12;      // 0..1022
  int n0 = nt * 64;
  int tid = threadIdx.x;
  int i = tid & 15, j = tid >> 4;
  float acc[4][4] = {};

  for (int ch = 0; ch < 4; ++ch) {
    int dirc = ch >> 1, koff = (ch & 1) * 64;
    {
      int bb = tid >> 2, p = tid & 3;
      const uint32_t* asrc = Hdw + ((size_t)(dirc * T_SEQ + t) * NB + bb) * 128 + koff + p * 4;
      const uint32_t* wsrc = WdH_dw + (size_t)(n0 + bb) * 256 + ch * 64 + p * 4;
      #pragma unroll
      for (int q = 0; q < 4; ++q) {
        *(uint4*)(&Asm[bb][p * 4 + q * 16]) = *(const uint4*)(asrc + q * 16);
        *(uint4*)(&Wsm[bb][p * 4 + q * 16]) = *(const uint4*)(wsrc + q * 16);
      }
    }
    __syncthreads();
    #pragma unroll
    for (int kc = 0; kc < 16; ++kc) {
      uint4 av[4], wv4[4];
      #pragma unroll
      for (int r = 0; r < 4; ++r) av[r]  = *(const uint4*)&Asm[i + 16 * r][kc * 4];
      #pragma unroll
      for (int s = 0; s < 4; ++s) wv4[s] = *(const uint4*)&Wsm[j + 16 * s][kc * 4];
      #pragma unroll
      for (int r = 0; r < 4; ++r)
        #pragma unroll
        for (int s = 0; s < 4; ++s) {
          acc[r][s] = fdot2f(av[r].x, wv4[s].x, acc[r][s]);
          acc[r][s] = fdot2f(av[r].y, wv4[s].y, acc[r][s]);
          acc[r][s] = fdot2f(av[r].z, wv4[s].z, acc[r][s]);
          acc[r][s] = fdot2f(av[r].w, wv4[s].w, acc[r][s]);
        }
    }
    __syncthreads();
  }
  #pragma unroll
  for (int r = 0; r < 4; ++r)
    #pragma unroll
    for (int s = 0; s < 4; ++s) {
      int m = i + 16 * r;
      int n = n0 + j + 16 * s;
      E[((size_t)t * NB + m) * DROWS + n] = (f16)(acc[r][s] + dbias[n]);
    }
}

// ---------------- decoder: 64 independent per-batch persistent WGs
__launch_bounds__(512, 2)
__global__ void k_dec(const float* __restrict__ mel, const f16* __restrict__ E,
                      const uint32_t* __restrict__ WmH_dw, const uint32_t* __restrict__ WfcH_dw,
                      const float* __restrict__ bfc, float* __restrict__ out) {
  __shared__ __align__(16) uint32_t pm[40];        // prev_mel 80 f16
  __shared__ float g_lds[768];
  __shared__ __align__(16) uint32_t h_sm[128];     // h 256 f16
  __shared__ float partial[80][2];
  __shared__ __align__(16) uint32_t wfc_sm[80 * 132];

  int b = blockIdx.x;
  int tid = threadIdx.x;
  int rA = (tid < 256) ? tid : (tid + 256);        // i rows or o rows
  int rB = tid + 256;                              // g rows (valid use only tid<256)

  uint4 wm0v[10], wm1v[10];
  {
    const uint4* p0 = (const uint4*)(WmH_dw + (size_t)rA * 40);
    const uint4* p1 = (const uint4*)(WmH_dw + (size_t)rB * 40);
    #pragma unroll
    for (int k = 0; k < 10; ++k) { wm0v[k] = p0[k]; wm1v[k] = p1[k]; }
  }
  for (int idx = tid; idx < 80 * 128; idx += 512) {
    int r = idx >> 7, k = idx & 127;
    wfc_sm[r * 132 + k] = WfcH_dw[idx];
  }
  if (tid < 40) {
    float m0 = mel[(size_t)b * T_SEQ * NMEL + 2 * tid];
    float m1 = mel[(size_t)b * T_SEQ * NMEL + 2 * tid + 1];
    f16x2 v; v[0] = (f16)m0; v[1] = (f16)m1;
    pm[tid] = __builtin_bit_cast(uint32_t, v);
  }
  __syncthreads();

  for (int t = 0; t < T_SEQ - 1; ++t) {
    const f16* Et = E + ((size_t)t * NB + b) * DROWS;
    float accA = (float)Et[rA];
    float accB = (tid < 256) ? (float)Et[rB] : 0.0f;
    const uint4* pm4 = (const uint4*)pm;
    #pragma unroll
    for (int k = 0; k < 10; ++k) {
      uint4 hp = pm4[k];
      accA = fdot2f(wm0v[k].x, hp.x, accA); accB = fdot2f(wm1v[k].x, hp.x, accB);
      accA = fdot2f(wm0v[k].y, hp.y, accA); accB = fdot2f(wm1v[k].y, hp.y, accB);
      accA = fdot2f(wm0v[k].z, hp.z, accA); accB = fdot2f(wm1v[k].z, hp.z, accB);
      accA = fdot2f(wm0v[k].w, hp.w, accA); accB = fdot2f(wm1v[k].w, hp.w, accB);
    }
    g_lds[(tid < 256) ? tid : (tid + 256)] = accA;
    if (tid < 256) g_lds[256 + tid] = accB;
    __syncthreads();

    if (tid < 256) {
      float gi = g_lds[tid], gg = g_lds[256 + tid], go = g_lds[512 + tid];
      float cc = sigm(gi) * tanhf(gg);
      float h  = sigm(go) * tanhf(cc);
      ((f16*)h_sm)[tid] = (f16)h;
    }
    __syncthreads();

    if (tid < 160) {
      int r = tid >> 1, q = tid & 1;
      const uint4* wrow = (const uint4*)&wfc_sm[r * 132 + q * 64];
      const uint4* hrow = (const uint4*)&h_sm[q * 64];
      float a0 = 0, a1 = 0, a2 = 0, a3 = 0;
      #pragma unroll
      for (int kk = 0; kk < 16; ++kk) {
        uint4 wq = wrow[kk]; uint4 hq = hrow[kk];
        a0 = fdot2f(wq.x, hq.x, a0); a1 = fdot2f(wq.y, hq.y, a1);
        a2 = fdot2f(wq.z, hq.z, a2); a3 = fdot2f(wq.w, hq.w, a3);
      }
      partial[r][q] = (a0 + a1) + (a2 + a3);
    }
    __syncthreads();

    if (tid < NMEL) {
      float o = partial[tid][0] + partial[tid][1] + bfc[tid];
      out[((size_t)b * (T_SEQ - 1) + t) * NMEL + tid] = o;
      ((f16*)pm)[tid] = (f16)o;
    }
    __syncthreads();
  }
}

// ---------------- host ----------------
extern "C" void kernel_launch(void* const* d_in, const int* in_sizes, int n_in,
                              void* d_out, int out_size, void* d_ws, size_t ws_size,
                              hipStream_t stream) {
  const int*   text_seq   = (const int*)d_in[0];
  const float* mel        = (const float*)d_in[1];
  const int*   speaker_id = (const int*)d_in[2];
  const float* emb_text   = (const float*)d_in[3];
  const float* emb_spk    = (const float*)d_in[4];
  const float* Wih_f = (const float*)d_in[5];
  const float* Whh_f = (const float*)d_in[6];
  const float* bih_f = (const float*)d_in[7];
  const float* bhh_f = (const float*)d_in[8];
  const float* Wih_b = (const float*)d_in[9];
  const float* Whh_b = (const float*)d_in[10];
  const float* bih_b = (const float*)d_in[11];
  const float* bhh_b = (const float*)d_in[12];
  const float* Wih_d = (const float*)d_in[13];
  const float* bih_d = (const float*)d_in[14];
  const float* bhh_d = (const float*)d_in[15];
  const float* Wfc   = (const float*)d_in[16];
  const float* bfc   = (const float*)d_in[17];
  float* out = (float*)d_out;

  char* base = (char*)d_ws;
  size_t off = 0;
  auto take = [&](size_t n) -> char* {
    off = (off + 255) & ~(size_t)255;
    char* r = base + off;
    off += n;
    return r;
  };
  float*        TP    = (float*)take((size_t)2 * VOCAB * GROWS * 4);
  float*        SP    = (float*)take((size_t)2 * NSPK * GROWS * 4);
  f16*          WhhH  = (f16*)take((size_t)2 * GROWS * HID * 2);
  f16*          WmH   = (f16*)take((size_t)DROWS * 80 * 2);
  f16*          WdH   = (f16*)take((size_t)DROWS * 512 * 2);
  f16*          WfcH  = (f16*)take((size_t)NMEL * HID * 2);
  float*        dbias = (float*)take((size_t)DROWS * 4);
  unsigned int* flags = (unsigned int*)take(256 * 4);
  f16*          Hh    = (f16*)take((size_t)2 * T_SEQ * NB * HID * 2);
  f16*          E     = (f16*)take((size_t)(T_SEQ - 1) * NB * DROWS * 2);
  if (off > ws_size) return;   // insufficient workspace -> fail visibly

  k_tp  <<<2 * VOCAB, 256, 0, stream>>>(Wih_f, Wih_b, emb_text, TP);
  k_sp  <<<2 * NSPK, 256, 0, stream>>>(Wih_f, Wih_b, bih_f, bhh_f, bih_b, bhh_b, emb_spk, SP);
  k_whh <<<2048, 256, 0, stream>>>(Whh_f, Whh_b, WhhH);
  k_decw<<<DROWS, 256, 0, stream>>>(Wih_d, bih_d, bhh_d, WmH, WdH, dbias);
  k_misc<<<80, 256, 0, stream>>>(Wfc, WfcH, flags);
  k_enc <<<256, 512, 0, stream>>>(text_seq, speaker_id, TP, SP,
                                  (const uint32_t*)WhhH, (uint32_t*)Hh, flags);
  k_eproj<<<(T_SEQ - 1) * 12, 256, 0, stream>>>((const uint32_t*)Hh,
                                                (const uint32_t*)WdH, dbias, E);
  k_dec <<<NB, 512, 0, stream>>>(mel, E, (const uint32_t*)WmH,
                                 (const uint32_t*)WfcH, bfc, out);
}

// Round 2
// 4158.278 us; speedup vs baseline: 1.8982x; 1.8982x over previous
//
#include <hip/hip_runtime.h>
#include <hip/hip_fp16.h>
#include <stdint.h>

#define T_SEQ 1024
#define NB    64
#define VOCAB 34
#define NSPK  128
#define DTXT  512
#define HID   256
#define NMEL  80
#define GROWS 1024   // 4*HID gate rows
#define DROWS 768    // decoder rows actually used: i,g,o

typedef _Float16 f16;
typedef _Float16 f16x2 __attribute__((ext_vector_type(2)));

__device__ __forceinline__ float fdot2f(uint32_t a, uint32_t b, float c) {
  return __builtin_amdgcn_fdot2(__builtin_bit_cast(f16x2, a),
                                __builtin_bit_cast(f16x2, b), c, false);
}
__device__ __forceinline__ float sigm(float x) { return 1.0f / (1.0f + __expf(-x)); }
__device__ __forceinline__ float tanhf_fast(float x) {
  float e = __expf(2.0f * x);
  return 1.0f - 2.0f / (e + 1.0f);
}

// ---------------- prep kernels ----------------

// TP[dir][v][row] = emb_text[v] . Wih[dir][row][0:512]
__global__ void k_tp(const float* __restrict__ Wf, const float* __restrict__ Wb,
                     const float* __restrict__ emb_text, float* __restrict__ TP) {
  int blk = blockIdx.x; int dir = blk / VOCAB; int v = blk - dir * VOCAB;
  const float* W = dir ? Wb : Wf;
  const float* e = emb_text + (size_t)v * DTXT;
  for (int r = threadIdx.x; r < GROWS; r += 256) {
    const float* wr = W + (size_t)r * 576;
    float a0 = 0, a1 = 0, a2 = 0, a3 = 0;
    for (int d = 0; d < DTXT; d += 4) {
      a0 += e[d] * wr[d];     a1 += e[d+1] * wr[d+1];
      a2 += e[d+2] * wr[d+2]; a3 += e[d+3] * wr[d+3];
    }
    TP[(size_t)(dir * VOCAB + v) * GROWS + r] = (a0 + a1) + (a2 + a3);
  }
}

// SP[dir][s][row] = emb_spk[s] . Wih[dir][row][512:576] + bih[row] + bhh[row]
__global__ void k_sp(const float* __restrict__ Wf, const float* __restrict__ Wb,
                     const float* __restrict__ bihf, const float* __restrict__ bhhf,
                     const float* __restrict__ bihb, const float* __restrict__ bhhb,
                     const float* __restrict__ emb_spk, float* __restrict__ SP) {
  int blk = blockIdx.x; int dir = blk >> 7; int s = blk & 127;
  const float* W  = dir ? Wb : Wf;
  const float* bi = dir ? bihb : bihf;
  const float* bh = dir ? bhhb : bhhf;
  const float* e  = emb_spk + (size_t)s * 64;
  for (int r = threadIdx.x; r < GROWS; r += 256) {
    const float* wr = W + (size_t)r * 576 + 512;
    float acc = bi[r] + bh[r];
    for (int d = 0; d < 64; ++d) acc += e[d] * wr[d];
    SP[(size_t)(dir * NSPK + s) * GROWS + r] = acc;
  }
}

// Whh (both dirs) -> f16, layout [2][1024][256]
__global__ void k_whh(const float* __restrict__ Whhf, const float* __restrict__ Whhb,
                      f16* __restrict__ WhhH) {
  int idx = blockIdx.x * 256 + threadIdx.x;
  if (idx < 2 * GROWS * HID) {
    int dir = idx >> 18; int rem = idx & (GROWS * HID - 1);
    WhhH[idx] = (f16)(dir ? Whhb[rem] : Whhf[rem]);
  }
}

// decoder weights, row-reordered to [i(256), g(256), o(256)] (f gate unused)
__global__ void k_decw(const float* __restrict__ Wih_d, const float* __restrict__ bih_d,
                       const float* __restrict__ bhh_d,
                       f16* __restrict__ WmH, f16* __restrict__ WdH, float* __restrict__ dbias) {
  int r = blockIdx.x;                 // 0..767
  int src = (r < 256) ? r : (r + 256);
  const float* w = Wih_d + (size_t)src * 592;
  for (int k = threadIdx.x; k < 592; k += 256) {
    float v = w[k];
    if (k < 80) WmH[(size_t)r * 80 + k] = (f16)v;
    else        WdH[(size_t)r * 512 + (k - 80)] = (f16)v;
  }
  if (threadIdx.x == 0) dbias[r] = bih_d[src] + bhh_d[src];
}

__global__ void k_misc(const float* __restrict__ Wfc, f16* __restrict__ WfcH) {
  int idx = blockIdx.x * 256 + threadIdx.x;
  if (idx < NMEL * HID) WfcH[idx] = (f16)Wfc[idx];
}

// ---------------- encoder: one WG per (dir,b) chain — NO cross-WG sync ----------------
// 128 WGs x 512 threads. Thread owns rows tid and tid+512.
// Per row: first 192 f16 weights in VGPRs (24 x uint4), last 64 f16 in LDS (XOR-swizzled).
__launch_bounds__(512, 2)
__global__ void k_enc(const int* __restrict__ text_seq, const int* __restrict__ speaker_id,
                      const float* __restrict__ TP, const float* __restrict__ SP,
                      const uint32_t* __restrict__ WhhH_dw,
                      uint32_t* __restrict__ Hdw) {          // Hhist [2][1024][64][128 dw] f16
  __shared__ __align__(16) uint32_t wtail[GROWS * 32];       // 128 KiB
  __shared__ __align__(16) uint32_t h_dw[128];               // 256 f16
  __shared__ float g_lds[GROWS];                             // 4 KiB
  __shared__ int   tseq[T_SEQ];                              // 4 KiB

  int wg = blockIdx.x;          // 0..127 = dir*64 + b
  int dir = wg >> 6, b = wg & 63;
  int tid = threadIdx.x;
  int rowA = tid, rowB = tid + 512;
  int sA = rowA & 7;            // == rowB & 7 (512 % 8 == 0)

  // VGPR-resident weights: first 96 dwords of each row
  uint4 wA[24], wB[24];
  {
    const uint4* pA = (const uint4*)(WhhH_dw + ((size_t)(dir << 10) + rowA) * 128);
    const uint4* pB = (const uint4*)(WhhH_dw + ((size_t)(dir << 10) + rowB) * 128);
    #pragma unroll
    for (int i = 0; i < 24; ++i) { wA[i] = pA[i]; wB[i] = pB[i]; }
    // tail: last 8 uint4 of each row -> LDS, XOR-swizzled within 8-row stripes
    #pragma unroll
    for (int j = 0; j < 8; ++j) {
      *(uint4*)((char*)wtail + rowA * 128 + ((j ^ sA) << 4)) = pA[24 + j];
      *(uint4*)((char*)wtail + rowB * 128 + ((j ^ sA) << 4)) = pB[24 + j];
    }
  }
  for (int i = tid; i < T_SEQ; i += 512) tseq[i] = text_seq[b * T_SEQ + i];
  if (tid < 128) h_dw[tid] = 0u;
  int spk = speaker_id[b];
  float spA = SP[(size_t)(dir * NSPK + spk) * GROWS + rowA];
  float spB = SP[(size_t)(dir * NSPK + spk) * GROWS + rowB];
  const float* TPd = TP + (size_t)dir * VOCAB * GROWS;
  float c_state = 0.0f;
  __syncthreads();

  int t0 = dir ? (T_SEQ - 1) : 0;
  float xA = TPd[(size_t)tseq[t0] * GROWS + rowA];
  float xB = TPd[(size_t)tseq[t0] * GROWS + rowB];

  for (int n = 0; n < T_SEQ; ++n) {
    int t = dir ? (T_SEQ - 1 - n) : n;
    float accA = xA + spA, accB = xB + spB;
    if (n < T_SEQ - 1) {                 // prefetch next step's x
      int tn = dir ? (T_SEQ - 2 - n) : (n + 1);
      int v = tseq[tn];
      xA = TPd[(size_t)v * GROWS + rowA];
      xB = TPd[(size_t)v * GROWS + rowB];
    }
    const uint4* h4 = (const uint4*)h_dw;
    #pragma unroll
    for (int c = 0; c < 24; ++c) {
      uint4 hv = h4[c];
      accA = fdot2f(wA[c].x, hv.x, accA); accB = fdot2f(wB[c].x, hv.x, accB);
      accA = fdot2f(wA[c].y, hv.y, accA); accB = fdot2f(wB[c].y, hv.y, accB);
      accA = fdot2f(wA[c].z, hv.z, accA); accB = fdot2f(wB[c].z, hv.z, accB);
      accA = fdot2f(wA[c].w, hv.w, accA); accB = fdot2f(wB[c].w, hv.w, accB);
    }
    #pragma unroll
    for (int j = 0; j < 8; ++j) {
      uint4 hv = h4[24 + j];
      uint4 ta = *(const uint4*)((char*)wtail + rowA * 128 + ((j ^ sA) << 4));
      uint4 tb = *(const uint4*)((char*)wtail + rowB * 128 + ((j ^ sA) << 4));
      accA = fdot2f(ta.x, hv.x, accA); accB = fdot2f(tb.x, hv.x, accB);
      accA = fdot2f(ta.y, hv.y, accA); accB = fdot2f(tb.y, hv.y, accB);
      accA = fdot2f(ta.z, hv.z, accA); accB = fdot2f(tb.z, hv.z, accB);
      accA = fdot2f(ta.w, hv.w, accA); accB = fdot2f(tb.w, hv.w, accB);
    }
    g_lds[rowA] = accA;
    g_lds[rowB] = accB;
    __syncthreads();                               // B1

    if (tid < HID) {
      float gi = g_lds[tid],       gf = g_lds[HID + tid];
      float gg = g_lds[2*HID + tid], go = g_lds[3*HID + tid];
      c_state = sigm(gf) * c_state + sigm(gi) * tanhf_fast(gg);
      float h = sigm(go) * tanhf_fast(c_state);
      ((f16*)h_dw)[tid] = (f16)h;
    }
    __syncthreads();                               // B2

    if (tid < 128)
      Hdw[((size_t)(dir * T_SEQ + t) * NB + b) * 128 + tid] = h_dw[tid];
  }
}

// ---------------- E projection: E[t][b][n] = cat(hf[t][b],hb[t][b]) . Wd[n] + dbias[n]
__launch_bounds__(256, 4)
__global__ void k_eproj(const uint32_t* __restrict__ Hdw, const uint32_t* __restrict__ WdH_dw,
                        const float* __restrict__ dbias, f16* __restrict__ E) {
  __shared__ __align__(16) uint32_t Asm[64][68];
  __shared__ __align__(16) uint32_t Wsm[64][68];
  int nt = blockIdx.x % 12;
  int t  = blockIdx.x / 12;      // 0..1022
  int n0 = nt * 64;
  int tid = threadIdx.x;
  int i = tid & 15, j = tid >> 4;
  float acc[4][4] = {};

  for (int ch = 0; ch < 4; ++ch) {
    int dirc = ch >> 1, koff = (ch & 1) * 64;
    {
      int bb = tid >> 2, p = tid & 3;
      const uint32_t* asrc = Hdw + ((size_t)(dirc * T_SEQ + t) * NB + bb) * 128 + koff + p * 4;
      const uint32_t* wsrc = WdH_dw + (size_t)(n0 + bb) * 256 + ch * 64 + p * 4;
      #pragma unroll
      for (int q = 0; q < 4; ++q) {
        *(uint4*)(&Asm[bb][p * 4 + q * 16]) = *(const uint4*)(asrc + q * 16);
        *(uint4*)(&Wsm[bb][p * 4 + q * 16]) = *(const uint4*)(wsrc + q * 16);
      }
    }
    __syncthreads();
    #pragma unroll
    for (int kc = 0; kc < 16; ++kc) {
      uint4 av[4], wv4[4];
      #pragma unroll
      for (int r = 0; r < 4; ++r) av[r]  = *(const uint4*)&Asm[i + 16 * r][kc * 4];
      #pragma unroll
      for (int s = 0; s < 4; ++s) wv4[s] = *(const uint4*)&Wsm[j + 16 * s][kc * 4];
      #pragma unroll
      for (int r = 0; r < 4; ++r)
        #pragma unroll
        for (int s = 0; s < 4; ++s) {
          acc[r][s] = fdot2f(av[r].x, wv4[s].x, acc[r][s]);
          acc[r][s] = fdot2f(av[r].y, wv4[s].y, acc[r][s]);
          acc[r][s] = fdot2f(av[r].z, wv4[s].z, acc[r][s]);
          acc[r][s] = fdot2f(av[r].w, wv4[s].w, acc[r][s]);
        }
    }
    __syncthreads();
  }
  #pragma unroll
  for (int r = 0; r < 4; ++r)
    #pragma unroll
    for (int s = 0; s < 4; ++s) {
      int m = i + 16 * r;
      int n = n0 + j + 16 * s;
      E[((size_t)t * NB + m) * DROWS + n] = (f16)(acc[r][s] + dbias[n]);
    }
}

// ---------------- decoder: 64 independent per-batch persistent WGs
__launch_bounds__(512, 2)
__global__ void k_dec(const float* __restrict__ mel, const f16* __restrict__ E,
                      const uint32_t* __restrict__ WmH_dw, const uint32_t* __restrict__ WfcH_dw,
                      const float* __restrict__ bfc, float* __restrict__ out) {
  __shared__ __align__(16) uint32_t pm[40];        // prev_mel 80 f16
  __shared__ float g_lds[768];
  __shared__ __align__(16) uint32_t h_sm[128];     // h 256 f16
  __shared__ float partial[80][2];
  __shared__ __align__(16) uint32_t wfc_sm[80 * 132];

  int b = blockIdx.x;
  int tid = threadIdx.x;
  int rA = (tid < 256) ? tid : (tid + 256);        // i rows or o rows
  int rB = tid + 256;                              // g rows (valid use only tid<256)

  uint4 wm0v[10], wm1v[10];
  {
    const uint4* p0 = (const uint4*)(WmH_dw + (size_t)rA * 40);
    const uint4* p1 = (const uint4*)(WmH_dw + (size_t)rB * 40);
    #pragma unroll
    for (int k = 0; k < 10; ++k) { wm0v[k] = p0[k]; wm1v[k] = p1[k]; }
  }
  for (int idx = tid; idx < 80 * 128; idx += 512) {
    int r = idx >> 7, k = idx & 127;
    wfc_sm[r * 132 + k] = WfcH_dw[idx];
  }
  if (tid < 40) {
    float m0 = mel[(size_t)b * T_SEQ * NMEL + 2 * tid];
    float m1 = mel[(size_t)b * T_SEQ * NMEL + 2 * tid + 1];
    f16x2 v; v[0] = (f16)m0; v[1] = (f16)m1;
    pm[tid] = __builtin_bit_cast(uint32_t, v);
  }
  __syncthreads();

  for (int t = 0; t < T_SEQ - 1; ++t) {
    const f16* Et = E + ((size_t)t * NB + b) * DROWS;
    float accA = (float)Et[rA];
    float accB = (tid < 256) ? (float)Et[rB] : 0.0f;
    const uint4* pm4 = (const uint4*)pm;
    #pragma unroll
    for (int k = 0; k < 10; ++k) {
      uint4 hp = pm4[k];
      accA = fdot2f(wm0v[k].x, hp.x, accA); accB = fdot2f(wm1v[k].x, hp.x, accB);
      accA = fdot2f(wm0v[k].y, hp.y, accA); accB = fdot2f(wm1v[k].y, hp.y, accB);
      accA = fdot2f(wm0v[k].z, hp.z, accA); accB = fdot2f(wm1v[k].z, hp.z, accB);
      accA = fdot2f(wm0v[k].w, hp.w, accA); accB = fdot2f(wm1v[k].w, hp.w, accB);
    }
    g_lds[(tid < 256) ? tid : (tid + 256)] = accA;
    if (tid < 256) g_lds[256 + tid] = accB;
    __syncthreads();

    if (tid < 256) {
      float gi = g_lds[tid], gg = g_lds[256 + tid], go = g_lds[512 + tid];
      float cc = sigm(gi) * tanhf_fast(gg);
      float h  = sigm(go) * tanhf_fast(cc);
      ((f16*)h_sm)[tid] = (f16)h;
    }
    __syncthreads();

    if (tid < 160) {
      int r = tid >> 1, q = tid & 1;
      const uint4* wrow = (const uint4*)&wfc_sm[r * 132 + q * 64];
      const uint4* hrow = (const uint4*)&h_sm[q * 64];
      float a0 = 0, a1 = 0, a2 = 0, a3 = 0;
      #pragma unroll
      for (int kk = 0; kk < 16; ++kk) {
        uint4 wq = wrow[kk]; uint4 hq = hrow[kk];
        a0 = fdot2f(wq.x, hq.x, a0); a1 = fdot2f(wq.y, hq.y, a1);
        a2 = fdot2f(wq.z, hq.z, a2); a3 = fdot2f(wq.w, hq.w, a3);
      }
      partial[r][q] = (a0 + a1) + (a2 + a3);
    }
    __syncthreads();

    if (tid < NMEL) {
      float o = partial[tid][0] + partial[tid][1] + bfc[tid];
      out[((size_t)b * (T_SEQ - 1) + t) * NMEL + tid] = o;
      ((f16*)pm)[tid] = (f16)o;
    }
    __syncthreads();
  }
}

// ---------------- host ----------------
extern "C" void kernel_launch(void* const* d_in, const int* in_sizes, int n_in,
                              void* d_out, int out_size, void* d_ws, size_t ws_size,
                              hipStream_t stream) {
  const int*   text_seq   = (const int*)d_in[0];
  const float* mel        = (const float*)d_in[1];
  const int*   speaker_id = (const int*)d_in[2];
  const float* emb_text   = (const float*)d_in[3];
  const float* emb_spk    = (const float*)d_in[4];
  const float* Wih_f = (const float*)d_in[5];
  const float* Whh_f = (const float*)d_in[6];
  const float* bih_f = (const float*)d_in[7];
  const float* bhh_f = (const float*)d_in[8];
  const float* Wih_b = (const float*)d_in[9];
  const float* Whh_b = (const float*)d_in[10];
  const float* bih_b = (const float*)d_in[11];
  const float* bhh_b = (const float*)d_in[12];
  const float* Wih_d = (const float*)d_in[13];
  const float* bih_d = (const float*)d_in[14];
  const float* bhh_d = (const float*)d_in[15];
  const float* Wfc   = (const float*)d_in[16];
  const float* bfc   = (const float*)d_in[17];
  float* out = (float*)d_out;

  char* base = (char*)d_ws;
  size_t off = 0;
  auto take = [&](size_t n) -> char* {
    off = (off + 255) & ~(size_t)255;
    char* r = base + off;
    off += n;
    return r;
  };
  float*        TP    = (float*)take((size_t)2 * VOCAB * GROWS * 4);
  float*        SP    = (float*)take((size_t)2 * NSPK * GROWS * 4);
  f16*          WhhH  = (f16*)take((size_t)2 * GROWS * HID * 2);
  f16*          WmH   = (f16*)take((size_t)DROWS * 80 * 2);
  f16*          WdH   = (f16*)take((size_t)DROWS * 512 * 2);
  f16*          WfcH  = (f16*)take((size_t)NMEL * HID * 2);
  float*        dbias = (float*)take((size_t)DROWS * 4);
  f16*          Hh    = (f16*)take((size_t)2 * T_SEQ * NB * HID * 2);
  f16*          E     = (f16*)take((size_t)(T_SEQ - 1) * NB * DROWS * 2);
  if (off > ws_size) return;   // insufficient workspace -> fail visibly

  k_tp  <<<2 * VOCAB, 256, 0, stream>>>(Wih_f, Wih_b, emb_text, TP);
  k_sp  <<<2 * NSPK, 256, 0, stream>>>(Wih_f, Wih_b, bih_f, bhh_f, bih_b, bhh_b, emb_spk, SP);
  k_whh <<<2048, 256, 0, stream>>>(Whh_f, Whh_b, WhhH);
  k_decw<<<DROWS, 256, 0, stream>>>(Wih_d, bih_d, bhh_d, WmH, WdH, dbias);
  k_misc<<<80, 256, 0, stream>>>(Wfc, WfcH);
  k_enc <<<128, 512, 0, stream>>>(text_seq, speaker_id, TP, SP,
                                  (const uint32_t*)WhhH, (uint32_t*)Hh);
  k_eproj<<<(T_SEQ - 1) * 12, 256, 0, stream>>>((const uint32_t*)Hh,
                                                (const uint32_t*)WdH, dbias, E);
  k_dec <<<NB, 512, 0, stream>>>(mel, E, (const uint32_t*)WmH,
                                 (const uint32_t*)WfcH, bfc, out);
}